// Round 1
// baseline (564.600 us; speedup 1.0000x reference)
//
#include <hip/hip_runtime.h>
#include <math.h>

#define NB 32
#define NL 512
#define NC 64
#define NG 3
#define NT 10000
#define NP 96
#define TOPM 20

// ---------------------------------------------------------------------------
// Kernel A: per-(b,c) multi-period stats -> normalized q [G,B,C,4] (fp64)
// lane = c, block = b. Loads are coalesced (64 lanes read 256B contiguous).
// Stats identities (offset-removed mg): mean = mean(cur)-last, std = std(cur),
// slope = (last-first)/511, absdiff = sum|cur[j]-cur[j-1]|/511.
// ---------------------------------------------------------------------------
__global__ __launch_bounds__(64) void qstat_kernel(const float* __restrict__ x,
                                                   double* __restrict__ q) {
  const int b = blockIdx.x;
  const int c = threadIdx.x;
  const float* xp = x + (size_t)b * NL * NC + c;
  double sum[3] = {0, 0, 0}, sumsq[3] = {0, 0, 0}, sumabs[3] = {0, 0, 0};
  double first[3] = {0, 0, 0}, prev[3] = {0, 0, 0};
  double acc2 = 0.0, acc4 = 0.0;
  for (int l = 0; l < NL; ++l) {
    double v = (double)xp[l * NC];
    {  // period 1 -> g index 2 (PERIODS=[4,2,1])
      sum[2] += v; sumsq[2] += v * v;
      if (l == 0) first[2] = v; else sumabs[2] += fabs(v - prev[2]);
      prev[2] = v;
    }
    acc2 += v;
    if ((l & 1) == 1) {  // period 2 -> g index 1
      double cur = acc2 * 0.5; acc2 = 0.0;
      sum[1] += cur; sumsq[1] += cur * cur;
      if ((l >> 1) == 0) first[1] = cur; else sumabs[1] += fabs(cur - prev[1]);
      prev[1] = cur;
    }
    acc4 += v;
    if ((l & 3) == 3) {  // period 4 -> g index 0
      double cur = acc4 * 0.25; acc4 = 0.0;
      if ((l >> 2) == 0) first[0] = cur; else sumabs[0] += fabs(cur - prev[0]);
      sum[0] += cur; sumsq[0] += cur * cur;
      prev[0] = cur;
    }
  }
  const double J[3] = {128.0, 256.0, 512.0};
  for (int g = 0; g < 3; ++g) {
    double mean = sum[g] / J[g];
    double var = sumsq[g] / J[g] - mean * mean;
    if (var < 0.0) var = 0.0;
    double s0 = mean - prev[g];                    // mean of offset-removed
    double s1 = sqrt(var);                         // std (population)
    double s2 = (prev[g] - first[g]) * (1.0 / 511.0);  // slope
    double s3 = sumabs[g] * (1.0 / 511.0);         // mean |diff|
    double n = sqrt(s0 * s0 + s1 * s1 + s2 * s2 + s3 * s3);
    double inv = 1.0 / fmax(n, 1e-12);
    double* qp = q + ((((size_t)g * NB) + b) * NC + c) * 4;
    qp[0] = s0 * inv; qp[1] = s1 * inv; qp[2] = s2 * inv; qp[3] = s3 * inv;
  }
}

// ---------------------------------------------------------------------------
// Kernel B: sim over a t-chunk + per-lane register top-20 (fp64).
// lane = c; wave = one b; 4 waves/block share the pool_state stream via L1.
// sim(b,c,t) = (1/3) * sum_g dot(q_g, p_g) / max(|p_g|, eps)
// Top-20 via gated unrolled carry-insertion: fully static register indexing.
// ---------------------------------------------------------------------------
__global__ __launch_bounds__(256) void sim_topk_kernel(
    const float* __restrict__ ps, const double* __restrict__ q,
    double* __restrict__ cval, int* __restrict__ cidx, int nch, int chunk) {
  const int wav = threadIdx.x >> 6;
  const int c = threadIdx.x & 63;
  const int b = blockIdx.y * 4 + wav;
  const int ch = blockIdx.x;
  double qv[3][4];
#pragma unroll
  for (int g = 0; g < 3; ++g) {
    const double* qp = q + ((((size_t)g * NB) + b) * NC + c) * 4;
    qv[g][0] = qp[0]; qv[g][1] = qp[1]; qv[g][2] = qp[2]; qv[g][3] = qp[3];
  }
  double val[TOPM]; int idx[TOPM];
#pragma unroll
  for (int m = 0; m < TOPM; ++m) { val[m] = -1e300; idx[m] = 0; }
  int t0 = ch * chunk;
  int t1 = t0 + chunk; if (t1 > NT) t1 = NT;
  for (int t = t0; t < t1; ++t) {
    double s = 0.0;
#pragma unroll
    for (int g = 0; g < 3; ++g) {
      const float4 pv = *reinterpret_cast<const float4*>(
          ps + ((((size_t)g * NT) + t) * NC + c) * 4);
      double p0 = pv.x, p1 = pv.y, p2 = pv.z, p3 = pv.w;
      double ss = p0 * p0 + p1 * p1 + p2 * p2 + p3 * p3;
      double dot = qv[g][0] * p0 + qv[g][1] * p1 + qv[g][2] * p2 + qv[g][3] * p3;
      s += dot / fmax(sqrt(ss), 1e-12);
    }
    s *= (1.0 / 3.0);
    if (s > val[TOPM - 1]) {  // gate: beats current min
      double cv = s; int ci = t;
#pragma unroll
      for (int m = 0; m < TOPM; ++m) {  // stable (strict >): ties keep lower t
        bool sw = cv > val[m];
        double tv = sw ? val[m] : cv; int ti = sw ? idx[m] : ci;
        val[m] = sw ? cv : val[m];    idx[m] = sw ? ci : idx[m];
        cv = tv; ci = ti;
      }
    }
  }
  double* vout = cval + ((((size_t)b * NC) + c) * nch + ch) * TOPM;
  int* iout = cidx + ((((size_t)b * NC) + c) * nch + ch) * TOPM;
#pragma unroll
  for (int m = 0; m < TOPM; ++m) { vout[m] = val[m]; iout[m] = idx[m]; }
}

// ---------------------------------------------------------------------------
// Kernel C: merge nch*20 candidates -> top-20, softmax, gather + output.
// One block per (b,c); thread 0 merges (chunk-ascending scan keeps tie order
// = lowest t first, matching jax.lax.top_k); 96 lanes do the P gather.
// ---------------------------------------------------------------------------
__global__ __launch_bounds__(128) void merge_gather_kernel(
    const double* __restrict__ cval, const int* __restrict__ cidx,
    const float* __restrict__ y, float* __restrict__ out, int nch) {
  const int c = blockIdx.x;
  const int b = blockIdx.y;
  __shared__ float w_s[TOPM];
  __shared__ int i_s[TOPM];
  if (threadIdx.x == 0) {
    double val[TOPM]; int idx[TOPM];
#pragma unroll
    for (int m = 0; m < TOPM; ++m) { val[m] = -1e300; idx[m] = 0; }
    const double* vin = cval + (((size_t)b * NC) + c) * nch * TOPM;
    const int* iin = cidx + (((size_t)b * NC) + c) * nch * TOPM;
    const int n = nch * TOPM;
    for (int k = 0; k < n; ++k) {
      double s = vin[k]; int t = iin[k];
      if (s > val[TOPM - 1]) {
        double cv = s; int ci = t;
#pragma unroll
        for (int m = 0; m < TOPM; ++m) {
          bool sw = cv > val[m];
          double tv = sw ? val[m] : cv; int ti = sw ? idx[m] : ci;
          val[m] = sw ? cv : val[m];    idx[m] = sw ? ci : idx[m];
          cv = tv; ci = ti;
        }
      }
    }
    // softmax(vals / 0.1)
    double mx = val[0];
    double e[TOPM]; double sum = 0.0;
#pragma unroll
    for (int m = 0; m < TOPM; ++m) { e[m] = exp((val[m] - mx) * 10.0); sum += e[m]; }
    double inv = 1.0 / sum;
#pragma unroll
    for (int m = 0; m < TOPM; ++m) { w_s[m] = (float)(e[m] * inv); i_s[m] = idx[m]; }
  }
  __syncthreads();
  const int p = threadIdx.x;
  if (p < NP) {
    float acc = 0.f;
#pragma unroll
    for (int m = 0; m < TOPM; ++m)
      acc += w_s[m] * y[(((size_t)i_s[m]) * NP + p) * NC + c];
    out[(((size_t)b * NP) + p) * NC + c] = acc;
  }
}

extern "C" void kernel_launch(void* const* d_in, const int* in_sizes, int n_in,
                              void* d_out, int out_size, void* d_ws, size_t ws_size,
                              hipStream_t stream) {
  const float* x = (const float*)d_in[0];
  const float* ps = (const float*)d_in[1];
  const float* y = (const float*)d_in[2];
  float* out = (float*)d_out;
  char* ws = (char*)d_ws;

  const size_t qbytes = (size_t)NG * NB * NC * 4 * sizeof(double);  // 196,608 B
  double* qbuf = (double*)ws;

  // choose t-chunk count that fits ws (target 32)
  int nch = 32;
  const size_t per_ch = (size_t)NB * NC * TOPM * (sizeof(double) + sizeof(int));
  if (ws_size > qbytes) {
    size_t mc = (ws_size - qbytes) / per_ch;
    if ((size_t)nch > mc) nch = (int)mc;
  } else {
    nch = 1;
  }
  if (nch < 1) nch = 1;
  double* cval = (double*)(ws + qbytes);
  int* cidx = (int*)(ws + qbytes + (size_t)NB * NC * (size_t)nch * TOPM * sizeof(double));
  int chunk = (NT + nch - 1) / nch;

  qstat_kernel<<<dim3(NB), dim3(NC), 0, stream>>>(x, qbuf);
  sim_topk_kernel<<<dim3(nch, NB / 4), dim3(256), 0, stream>>>(ps, qbuf, cval, cidx, nch, chunk);
  merge_gather_kernel<<<dim3(NC, NB), dim3(128), 0, stream>>>(cval, cidx, y, out, nch);
}